// Round 7
// baseline (252.775 us; speedup 1.0000x reference)
//
#include <hip/hip_runtime.h>
#include <stdint.h>

#define TT 512
#define BB 32
#define EE 512
#define HH 2048

typedef __attribute__((ext_vector_type(8))) short short8;   // 8 x bf16 (4 VGPRs)
typedef __attribute__((ext_vector_type(4))) float f32x4;    // MFMA accumulator

// LDS geometry (in shorts)
#define XROW 528            // 512 data + 16 pad: measured 0 bank conflicts (R1/R3/R6);
                            // 520 gave 8.4M conflicts (R4).
#define XBUF (16 * XROW)    // one 16-t chunk buffer = 8448 shorts (16.5 KB)

static __device__ __forceinline__ unsigned short f2bf(float f) {
    union { float f; unsigned u; } v; v.f = f;
    unsigned u = v.u;
    unsigned r = u + 0x7FFFu + ((u >> 16) & 1u);   // round-to-nearest-even
    return (unsigned short)(r >> 16);
}

static __device__ __forceinline__ float fast_exp(float x) {
    return __builtin_amdgcn_exp2f(x * 1.44269504f);
}
static __device__ __forceinline__ float fast_rcp(float x) {
    return __builtin_amdgcn_rcpf(x);
}

// Async global->LDS DMA, 16 B/lane (wave-uniform LDS base + lane*16).
// Verified correct R4/R6.
static __device__ __forceinline__ void load_lds16(const unsigned short* g, unsigned short* l) {
    __builtin_amdgcn_global_load_lds(
        (const __attribute__((address_space(1))) unsigned int*)(uintptr_t)g,
        (__attribute__((address_space(3))) unsigned int*)(uintptr_t)l,
        16, 0, 0);
}

// ---------------------------------------------------------------------------
// Pre-kernel: convert sent (T,B,E) fp32 to bf16 in ws. X ONLY now (W is
// converted inside qrnn's preamble) — tests whether the stable ~65 us
// convert-gap is BW-bound (should halve) or fixed overhead (won't move).
// ---------------------------------------------------------------------------
__global__ void convert_inputs(const float* __restrict__ X,
                               unsigned short* __restrict__ Xb) {
    int i = (blockIdx.x * blockDim.x + threadIdx.x) * 8;
    float4 v0 = *(const float4*)(X + i);
    float4 v1 = *(const float4*)(X + i + 4);
    union { short8 s; unsigned short u[8]; } o;
    o.u[0] = f2bf(v0.x); o.u[1] = f2bf(v0.y); o.u[2] = f2bf(v0.z); o.u[3] = f2bf(v0.w);
    o.u[4] = f2bf(v1.x); o.u[5] = f2bf(v1.y); o.u[6] = f2bf(v1.z); o.u[7] = f2bf(v1.w);
    *(short8*)(Xb + i) = o.s;
}

// ---------------------------------------------------------------------------
// Fused QRNN kernel, K-split, SOFTWARE-PIPELINED TAIL.
// Block = (batch b, 32 h-cols), 4 waves = 2 h-tiles x 2 k-halves.
// R6 post-mortem: the tail (activations+scan, ~700 serial cyc) depended on
// the just-issued MFMAs, so it was exposed in every chunk period and blocks
// phase-locked (wall ~2000 cyc/chunk vs 932 MFMA). Fix: run tail(ch-1) in
// iteration ch, BEFORE the barrier — it uses only saved registers + exch,
// so it issues while chunk ch's non-dependent MFMAs drain.
// Iteration ch:  stage(ch+1) | MFMA(ch) | tail(ch-1) [s=0] | publish(ch)
//                [s=1] | barrier | save acc(ch).
// exch hazards: slot ch&1 written at publish(ch), read at tail in iter ch+1
// (after barrier(ch)), rewritten at publish(ch+2) — barrier(ch+1) separates.
// ---------------------------------------------------------------------------
__launch_bounds__(256, 2)
__global__ void qrnn_fused(const unsigned short* __restrict__ Xb, // bf16 (T,B,E)
                           const float* __restrict__ Wf,          // fp32 (3H,E)
                           const float* __restrict__ bias,        // (3H)
                           float* __restrict__ out)               // (B,H) fp32
{
    __shared__ unsigned short xlds[2 * XBUF];      // 33,792 B
    __shared__ float exch[2][2][64][12];           // 12,288 B  (total 46,080 B)

    const int tid  = threadIdx.x;
    const int wv   = tid >> 6;         // wave 0..3
    const int lane = tid & 63;
    const int q    = lane >> 4;        // quad 0..3
    const int c    = lane & 15;        // column within 16x16 tile
    const int hi   = wv >> 1;          // h-tile 0..1
    const int s    = wv & 1;           // k-half 0..1
    const int b    = blockIdx.y;
    const int h    = blockIdx.x * 32 + hi * 16 + c;

    // ---- preload W fragments (this wave's K half) from FP32, cvt, pin in AGPRs ----
    // B-frag layout for 16x16x32: lane holds n = lane&15 (= h), k = q*8 + j.
    short8 wz[8], wf[8], wo[8];
    {
        const float* wzr = Wf + (size_t)h * EE            + s * 256;
        const float* wfr = Wf + (size_t)(HH + h) * EE     + s * 256;
        const float* wor = Wf + (size_t)(2 * HH + h) * EE + s * 256;
#pragma unroll
        for (int k = 0; k < 8; ++k) {
            int e0 = k * 32 + q * 8;
            union { short8 s8; unsigned short u[8]; } pz, pf, po;
#pragma unroll
            for (int j = 0; j < 8; ++j) {
                pz.u[j] = f2bf(wzr[e0 + j]);
                pf.u[j] = f2bf(wfr[e0 + j]);
                po.u[j] = f2bf(wor[e0 + j]);
            }
            wz[k] = pz.s8; wf[k] = pf.s8; wo[k] = po.s8;
        }
    }
    // Liveness pin in AGPR class (R3/R4/R6-verified: resident, no spill).
#pragma unroll
    for (int k = 0; k < 8; ++k) {
        asm volatile("" : "+a"(wz[k]), "+a"(wf[k]), "+a"(wo[k]));
    }

    const float b0 = (s == 0) ? bias[h]          : 0.0f;
    const float b1 = (s == 0) ? bias[HH + h]     : 0.0f;
    const float b2 = (s == 0) ? bias[2 * HH + h] : 0.0f;

    float carry = 0.0f;
    float vmax  = -1e30f;

    // ---- staging: wave wv owns rows wv*4 .. wv*4+3 of each 16-t chunk ----
    const unsigned short* g0 = Xb + ((size_t)(wv * 4) * BB + b) * EE + lane * 8;
    unsigned short* l0 = &xlds[(wv * 4) * XROW];

    auto stage = [&](int n, int slot) {
        const unsigned short* g = g0 + (size_t)n * (16 * BB * EE);
        unsigned short* l = l0 + slot * XBUF;
#pragma unroll
        for (int i = 0; i < 4; ++i)
            load_lds16(g + (size_t)i * (BB * EE), l + i * XROW);
    };

    stage(0, 0);
    __syncthreads();

    f32x4 yz = {0,0,0,0}, yf = {0,0,0,0}, yo = {0,0,0,0};  // saved acc (ch-1)

    for (int ch = 0; ch <= 32; ++ch) {
        const int buf = ch & 1;
        if (ch < 31) stage(ch + 1, buf ^ 1);

        // ---- MFMA for chunk ch (prefetch all 8 A-frags, then burst) ----
        f32x4 az, af, ao;
        if (ch < 32) {
            const unsigned short* Abase = &xlds[buf * XBUF + c * XROW + s * 256 + q * 8];
            short8 a[8];
#pragma unroll
            for (int k = 0; k < 8; ++k)
                a[k] = *(const short8*)(Abase + k * 32);

            az = (f32x4){b0, b0, b0, b0};
            af = (f32x4){b1, b1, b1, b1};
            ao = (f32x4){b2, b2, b2, b2};
#pragma unroll
            for (int k = 0; k < 8; ++k) {
                az = __builtin_amdgcn_mfma_f32_16x16x32_bf16(a[k], wz[k], az, 0, 0, 0);
                af = __builtin_amdgcn_mfma_f32_16x16x32_bf16(a[k], wf[k], af, 0, 0, 0);
                ao = __builtin_amdgcn_mfma_f32_16x16x32_bf16(a[k], wo[k], ao, 0, 0, 0);
            }
        }

        // ---- tail for chunk ch-1 (s=0): independent of the MFMAs above,
        //      issues while they drain. Uses yz/yf/yo + exch[(ch-1)&1]. ----
        if (ch > 0 && s == 0) {
            const int eb = (ch - 1) & 1;
            const float* e = &exch[eb][hi][lane][0];
            f32x4 pz = *(const f32x4*)(e);
            f32x4 pf = *(const f32x4*)(e + 4);
            f32x4 po = *(const f32x4*)(e + 8);
            f32x4 tz = yz + pz, tf = yf + pf, to = yo + po;

            float aa[4], mm[4], oo[4];
#pragma unroll
            for (int r = 0; r < 4; ++r) {
                float e2 = fast_exp(2.0f * tz[r]);
                float z  = 1.0f - 2.0f * fast_rcp(e2 + 1.0f);  // tanh
                float f  = fast_rcp(1.0f + fast_exp(-tf[r]));  // sigmoid
                float o  = fast_rcp(1.0f + fast_exp(-to[r]));  // sigmoid
                aa[r] = f * z;
                mm[r] = 1.0f - f;
                oo[r] = o;
            }

            // affine scan: compose 4 steps, scan across quads
            float A = aa[0], M = mm[0];
#pragma unroll
            for (int r = 1; r < 4; ++r) { A = aa[r] + mm[r] * A; M = mm[r] * M; }

            float Ap = __shfl_up(A, 16, 64), Mp = __shfl_up(M, 16, 64);
            if (q >= 1) { A = A + M * Ap; M = M * Mp; }
            Ap = __shfl_up(A, 32, 64); Mp = __shfl_up(M, 32, 64);
            if (q >= 2) { A = A + M * Ap; M = M * Mp; }
            float Ae = __shfl_up(A, 16, 64), Me = __shfl_up(M, 16, 64);
            if (q == 0) { Ae = 0.0f; Me = 1.0f; }
            float cc = Ae + Me * carry;

#pragma unroll
            for (int r = 0; r < 4; ++r) {
                cc = aa[r] + mm[r] * cc;
                vmax = fmaxf(vmax, oo[r] * cc);
            }

            float cend = A + M * carry;
            carry = __shfl(cend, 48 + c, 64);
        }

        // ---- s=1 publishes chunk ch partials into exch slot ch&1 ----
        if (ch < 32 && s == 1) {
            float* e = &exch[buf][hi][lane][0];
            *(f32x4*)(e)     = az;
            *(f32x4*)(e + 4) = af;
            *(f32x4*)(e + 8) = ao;
        }

        if (ch < 32) __syncthreads();

        // ---- save acc for next iteration's tail ----
        if (ch < 32 && s == 0) { yz = az; yf = af; yo = ao; }
    }

    if (s == 0) {
        vmax = fmaxf(vmax, __shfl_xor(vmax, 16, 64));
        vmax = fmaxf(vmax, __shfl_xor(vmax, 32, 64));
        if (q == 0) out[(size_t)b * HH + h] = vmax;
    }
}

// ---------------------------------------------------------------------------
extern "C" void kernel_launch(void* const* d_in, const int* in_sizes, int n_in,
                              void* d_out, int out_size, void* d_ws, size_t ws_size,
                              hipStream_t stream) {
    const float* sent = (const float*)d_in[0];
    // d_in[1] = lengths (unused by the math)
    const float* W    = (const float*)d_in[2];
    const float* bias = (const float*)d_in[3];
    float* out        = (float*)d_out;

    const int nX = TT * BB * EE;        // 8,388,608
    unsigned short* Xb = (unsigned short*)d_ws;

    convert_inputs<<<nX / 8 / 256, 256, 0, stream>>>(sent, Xb);

    dim3 grid(HH / 32, BB);             // (64, 32) = 2048 blocks
    qrnn_fused<<<grid, 256, 0, stream>>>(Xb, W, bias, out);
}

// Round 9
// 230.965 us; speedup vs baseline: 1.0944x; 1.0944x over previous
//
#include <hip/hip_runtime.h>
#include <stdint.h>

#define TT 512
#define BB 32
#define EE 512
#define HH 2048

typedef __attribute__((ext_vector_type(8))) short short8;   // 8 x bf16 (4 VGPRs)
typedef __attribute__((ext_vector_type(4))) float f32x4;    // MFMA accumulator

// LDS geometry (shorts). XROW=528 measured 0 bank conflicts (R1/R3/R6);
// 520 gave 8.4M conflicts (R4).
#define XROW 528
#define XBUF (32 * XROW)     // ONE 32-t chunk buffer = 16,896 shorts (33,792 B)

static __device__ __forceinline__ unsigned short f2bf(float f) {
    union { float f; unsigned u; } v; v.f = f;
    unsigned u = v.u;
    unsigned r = u + 0x7FFFu + ((u >> 16) & 1u);   // round-to-nearest-even
    return (unsigned short)(r >> 16);
}
static __device__ __forceinline__ float fast_exp(float x) {
    return __builtin_amdgcn_exp2f(x * 1.44269504f);
}
static __device__ __forceinline__ float fast_rcp(float x) {
    return __builtin_amdgcn_rcpf(x);
}
// Async global->LDS DMA, 16 B/lane (wave-uniform LDS base + lane*16). R4/R6-verified.
static __device__ __forceinline__ void load_lds16(const unsigned short* g, unsigned short* l) {
    __builtin_amdgcn_global_load_lds(
        (const __attribute__((address_space(1))) unsigned int*)(uintptr_t)g,
        (__attribute__((address_space(3))) unsigned int*)(uintptr_t)l,
        16, 0, 0);
}

// ---------------------------------------------------------------------------
// Pre-kernel: convert sent (T,B,E) and W (3H,E) fp32 -> bf16 in ws (R6-proven).
// ---------------------------------------------------------------------------
__global__ void convert_inputs(const float* __restrict__ X,
                               const float* __restrict__ W,
                               unsigned short* __restrict__ Xb,
                               unsigned short* __restrict__ Wb) {
    const int nX = TT * BB * EE;              // 8,388,608 (divisible by 8)
    int i = (blockIdx.x * blockDim.x + threadIdx.x) * 8;
    const float* src;
    unsigned short* dst;
    int j;
    if (i < nX) { src = X; dst = Xb; j = i; }
    else        { src = W; dst = Wb; j = i - nX; }
    float4 v0 = *(const float4*)(src + j);
    float4 v1 = *(const float4*)(src + j + 4);
    union { short8 s; unsigned short u[8]; } o;
    o.u[0] = f2bf(v0.x); o.u[1] = f2bf(v0.y); o.u[2] = f2bf(v0.z); o.u[3] = f2bf(v0.w);
    o.u[4] = f2bf(v1.x); o.u[5] = f2bf(v1.y); o.u[6] = f2bf(v1.z); o.u[7] = f2bf(v1.w);
    *(short8*)(dst + j) = o.s;
}

// ---------------------------------------------------------------------------
// Fused QRNN, K-split, TC=32 (2 m-tiles/chunk), SINGLE-BUFFERED X.
// Block = (batch b, 32 h-cols), 4 waves = 2 h-tiles x 2 k-halves. Standard
// launch (R8's cooperative variant never launched).
// Per 32-t chunk (2 barriers, vs R6's 2 per 16 t — halves tail exposures):
//   A-prefetch (16 ds_read_b128 -> 64 regs, BOTH m-tiles)
//   B1 = __syncthreads  [A-reads(ch) done -> DMA may overwrite;
//                        tail-exch-reads(ch-1) done -> publish(ch) safe]
//   stage(ch+1) DMA into the SAME buffer | 48 MFMAs from registers
//   publish partials (s=1)
//   B2 = __syncthreads  [full vmcnt drain: DMA(ch+1) landed before its
//                        A-prefetch; publish visible before tail]
//   tail (s=0): activations + 2-tile affine scan + running max — runs after
//   B2 so s!=0 waves race ahead into chunk ch+1 (R6-style overlap).
// exch: single buffer, row stride 28 floats (16B-aligned, worst 2-way bank
// alias = free per m136). LDS total 48,128 B (<64 KB, 2 blocks/CU at (256,2)).
// ---------------------------------------------------------------------------
__launch_bounds__(256, 2)
__global__ void qrnn_fused(const unsigned short* __restrict__ Xb, // bf16 (T,B,E)
                           const unsigned short* __restrict__ Wb, // bf16 (3H,E)
                           const float* __restrict__ bias,        // (3H)
                           float* __restrict__ out)               // (B,H) fp32
{
    __shared__ unsigned short xlds[XBUF];      // 33,792 B
    __shared__ float exch[2][64][28];          // 14,336 B (total 48,128 B)

    const int tid  = threadIdx.x;
    const int wv   = tid >> 6;         // wave 0..3
    const int lane = tid & 63;
    const int q    = lane >> 4;        // quad 0..3
    const int c    = lane & 15;        // column within 16x16 tile
    const int hi   = wv >> 1;          // h-tile 0..1
    const int s    = wv & 1;           // k-half 0..1
    const int b    = blockIdx.y;
    const int h    = blockIdx.x * 32 + hi * 16 + c;

    // ---- preload W fragments (this wave's K half); pin into AGPRs ----
    // B-frag 16x16x32: lane holds n = lane&15 (= h), k = q*8 + j.
    short8 wz[8], wf[8], wo[8];
    {
        const unsigned short* wzr = Wb + (size_t)h * EE            + s * 256;
        const unsigned short* wfr = Wb + (size_t)(HH + h) * EE     + s * 256;
        const unsigned short* wor = Wb + (size_t)(2 * HH + h) * EE + s * 256;
#pragma unroll
        for (int k = 0; k < 8; ++k) {
            int e0 = k * 32 + q * 8;
            wz[k] = *(const short8*)(wzr + e0);
            wf[k] = *(const short8*)(wfr + e0);
            wo[k] = *(const short8*)(wor + e0);
        }
    }
    // Liveness pin in AGPR class (R3/R4/R6-verified: resident, no spill).
#pragma unroll
    for (int k = 0; k < 8; ++k) {
        asm volatile("" : "+a"(wz[k]), "+a"(wf[k]), "+a"(wo[k]));
    }

    const float b0 = (s == 0) ? bias[h]          : 0.0f;
    const float b1 = (s == 0) ? bias[HH + h]     : 0.0f;
    const float b2 = (s == 0) ? bias[2 * HH + h] : 0.0f;

    float carry = 0.0f;
    float vmax  = -1e30f;

    // ---- staging: wave wv owns rows wv*8 .. wv*8+7 of each 32-t chunk ----
    const unsigned short* g0 = Xb + ((size_t)(wv * 8) * BB + b) * EE + lane * 8;
    unsigned short* l0 = &xlds[(wv * 8) * XROW];
    auto stage = [&](int n) {
        const unsigned short* g = g0 + (size_t)n * (32 * BB * EE);
#pragma unroll
        for (int i = 0; i < 8; ++i)
            load_lds16(g + (size_t)i * (BB * EE), l0 + i * XROW);
    };

    stage(0);
    __syncthreads();

#pragma unroll 1
    for (int ch = 0; ch < 16; ++ch) {
        // ---- A-prefetch: BOTH m-tiles into registers (16 x ds_read_b128) ----
        // lane holds m = lane&15 (= t within tile), k = q*8 + j
        const unsigned short* Ab = &xlds[c * XROW + s * 256 + q * 8];
        short8 a0[8], a1[8];
#pragma unroll
        for (int k = 0; k < 8; ++k) {
            a0[k] = *(const short8*)(Ab + k * 32);
            a1[k] = *(const short8*)(Ab + 16 * XROW + k * 32);
        }

        __syncthreads();   // B1 (see header)

        if (ch < 15) stage(ch + 1);   // DMA into the same buffer, under MFMAs

        // ---- MFMA burst: 48 MFMAs, 6 independent accumulator chains ----
        f32x4 az0 = {b0,b0,b0,b0}, af0 = {b1,b1,b1,b1}, ao0 = {b2,b2,b2,b2};
        f32x4 az1 = {b0,b0,b0,b0}, af1 = {b1,b1,b1,b1}, ao1 = {b2,b2,b2,b2};
#pragma unroll
        for (int k = 0; k < 8; ++k) {
            az0 = __builtin_amdgcn_mfma_f32_16x16x32_bf16(a0[k], wz[k], az0, 0, 0, 0);
            az1 = __builtin_amdgcn_mfma_f32_16x16x32_bf16(a1[k], wz[k], az1, 0, 0, 0);
            af0 = __builtin_amdgcn_mfma_f32_16x16x32_bf16(a0[k], wf[k], af0, 0, 0, 0);
            af1 = __builtin_amdgcn_mfma_f32_16x16x32_bf16(a1[k], wf[k], af1, 0, 0, 0);
            ao0 = __builtin_amdgcn_mfma_f32_16x16x32_bf16(a0[k], wo[k], ao0, 0, 0, 0);
            ao1 = __builtin_amdgcn_mfma_f32_16x16x32_bf16(a1[k], wo[k], ao1, 0, 0, 0);
        }

        // ---- s=1 publishes its 6 partial f32x4 ----
        if (s == 1) {
            float* e = &exch[hi][lane][0];
            *(f32x4*)(e +  0) = az0;  *(f32x4*)(e +  4) = af0;  *(f32x4*)(e +  8) = ao0;
            *(f32x4*)(e + 12) = az1;  *(f32x4*)(e + 16) = af1;  *(f32x4*)(e + 20) = ao1;
        }

        __syncthreads();   // B2 (see header)

        // ---- s=0 tail: t = mt*16 + q*4 + r, column h ----
        if (s == 0) {
            const float* e = &exch[hi][lane][0];
            f32x4 tz0 = az0 + *(const f32x4*)(e +  0);
            f32x4 tf0 = af0 + *(const f32x4*)(e +  4);
            f32x4 to0 = ao0 + *(const f32x4*)(e +  8);
            f32x4 tz1 = az1 + *(const f32x4*)(e + 12);
            f32x4 tf1 = af1 + *(const f32x4*)(e + 16);
            f32x4 to1 = ao1 + *(const f32x4*)(e + 20);

            float aa[2][4], mm[2][4], oo[2][4];
#pragma unroll
            for (int r = 0; r < 4; ++r) {
                float e2 = fast_exp(2.0f * tz0[r]);
                float z  = 1.0f - 2.0f * fast_rcp(e2 + 1.0f);
                float f  = fast_rcp(1.0f + fast_exp(-tf0[r]));
                oo[0][r] = fast_rcp(1.0f + fast_exp(-to0[r]));
                aa[0][r] = f * z;  mm[0][r] = 1.0f - f;
                float e2b = fast_exp(2.0f * tz1[r]);
                float zb  = 1.0f - 2.0f * fast_rcp(e2b + 1.0f);
                float fb  = fast_rcp(1.0f + fast_exp(-tf1[r]));
                oo[1][r] = fast_rcp(1.0f + fast_exp(-to1[r]));
                aa[1][r] = fb * zb;  mm[1][r] = 1.0f - fb;
            }

            // local compose per m-tile
            float A0 = aa[0][0], M0 = mm[0][0], A1 = aa[1][0], M1 = mm[1][0];
#pragma unroll
            for (int r = 1; r < 4; ++r) {
                A0 = aa[0][r] + mm[0][r] * A0;  M0 = mm[0][r] * M0;
                A1 = aa[1][r] + mm[1][r] * A1;  M1 = mm[1][r] * M1;
            }
            // quad-scan both pairs (inclusive I(q))
            float Ap, Mp, Bp, Np;
            Ap = __shfl_up(A0, 16, 64); Mp = __shfl_up(M0, 16, 64);
            Bp = __shfl_up(A1, 16, 64); Np = __shfl_up(M1, 16, 64);
            if (q >= 1) { A0 = A0 + M0 * Ap; M0 *= Mp; A1 = A1 + M1 * Bp; M1 *= Np; }
            Ap = __shfl_up(A0, 32, 64); Mp = __shfl_up(M0, 32, 64);
            Bp = __shfl_up(A1, 32, 64); Np = __shfl_up(M1, 32, 64);
            if (q >= 2) { A0 = A0 + M0 * Ap; M0 *= Mp; A1 = A1 + M1 * Bp; M1 *= Np; }
            // chunk-full compositions from q=3 lanes (per column c)
            float fA0 = __shfl(A0, 48 + c, 64), fM0 = __shfl(M0, 48 + c, 64);
            float fA1 = __shfl(A1, 48 + c, 64), fM1 = __shfl(M1, 48 + c, 64);
            // exclusive prefixes (I(q-1))
            float eA0 = __shfl_up(A0, 16, 64), eM0 = __shfl_up(M0, 16, 64);
            float eA1 = __shfl_up(A1, 16, 64), eM1 = __shfl_up(M1, 16, 64);
            if (q == 0) { eA0 = 0.0f; eM0 = 1.0f; eA1 = 0.0f; eM1 = 1.0f; }

            // mt0 replay
            float cc = eA0 + eM0 * carry;
#pragma unroll
            for (int r = 0; r < 4; ++r) {
                cc = aa[0][r] + mm[0][r] * cc;
                vmax = fmaxf(vmax, oo[0][r] * cc);
            }
            // mt1 replay (prefix = eI1 o full0 o carry)
            float base1 = fA0 + fM0 * carry;    // c after t=15 of this chunk
            cc = eA1 + eM1 * base1;
#pragma unroll
            for (int r = 0; r < 4; ++r) {
                cc = aa[1][r] + mm[1][r] * cc;
                vmax = fmaxf(vmax, oo[1][r] * cc);
            }
            carry = fA1 + fM1 * base1;          // all lanes of column agree
        }
    }

    if (s == 0) {
        vmax = fmaxf(vmax, __shfl_xor(vmax, 16, 64));
        vmax = fmaxf(vmax, __shfl_xor(vmax, 32, 64));
        if (q == 0) out[(size_t)b * HH + h] = vmax;
    }
}

// ---------------------------------------------------------------------------
extern "C" void kernel_launch(void* const* d_in, const int* in_sizes, int n_in,
                              void* d_out, int out_size, void* d_ws, size_t ws_size,
                              hipStream_t stream) {
    const float* sent = (const float*)d_in[0];
    // d_in[1] = lengths (unused by the math)
    const float* W    = (const float*)d_in[2];
    const float* bias = (const float*)d_in[3];
    float* out        = (float*)d_out;

    const int nX = TT * BB * EE;        // 8,388,608
    const int nW = 3 * HH * EE;         // 3,145,728
    unsigned short* Xb = (unsigned short*)d_ws;
    unsigned short* Wb = Xb + nX;       // 16 MiB offset, 16B-aligned

    int totalVec = (nX + nW) / 8;       // 1,441,792 threads, exact cover
    convert_inputs<<<totalVec / 256, 256, 0, stream>>>(sent, W, Xb, Wb);

    dim3 grid(HH / 32, BB);             // (64, 32) = 2048 blocks
    qrnn_fused<<<grid, 256, 0, stream>>>(Xb, Wb, bias, out);
}